// Round 19
// baseline (155.506 us; speedup 1.0000x reference)
//
#include <hip/hip_runtime.h>
#include <hip/hip_bf16.h>
#include <math.h>

#define HID   128
#define NG    50
#define TN    8192          // table entries (nearest-neighbor lookup)
#define TMAXD 16.0f         // table covers d in [0, 16)
#define TSPB  16            // samples per block in table branch
#define TBLB  512           // table blocks (TN / TSPB)
#define NRG   16            // hist/scatter row-ranges
#define NSL   32            // hist/scatter edge-slices (NRG*NSL = 512 blocks)
#define SCAN_CHUNK 1024

typedef __attribute__((ext_vector_type(8))) short bf16x8;
typedef __attribute__((ext_vector_type(4))) float f32x4;
typedef __attribute__((ext_vector_type(4))) int   i32x4;
typedef unsigned short u16;
typedef unsigned int   u32;

#define LOG2F 0.69314718056f

__device__ __forceinline__ float sspf(float v) {
    if (v > 15.f) return v - LOG2F;
    return __logf(1.f + __expf(v)) - LOG2F;
}

__device__ __forceinline__ u16 f2bf(float f) {
    __hip_bfloat16 h = __float2bfloat16(f);
    return *reinterpret_cast<u16*>(&h);
}
__device__ __forceinline__ float bf2f(u32 v) {
    union { u32 u; float f; } x; x.u = v << 16; return x.f;
}

union K1Smem {
    struct { float sattr[TSPB][64]; float st1[TSPB][128]; } tb;   // 12 KB
    int hcnt[3328];                                               // 13.3 KB
};

// ===========================================================================
// K1: [0,TBLB) table | [+512) 2-D hist (LDS atomics) | [+192) transposes |
//     [+nrec) rec[e] = (tbl_idx<<16)|col, coalesced, no atomics
// ===========================================================================
__global__ __launch_bounds__(256) void k1_table_hist_prep(
    const float* __restrict__ w1, const float* __restrict__ b1,
    const float* __restrict__ w2, const float* __restrict__ b2,
    u16* __restrict__ Tn,
    const int* __restrict__ eidx, int* __restrict__ cntp,   // [NSL][N]
    const float* __restrict__ pos, u32* __restrict__ rec,
    const float* __restrict__ lin1, const float* __restrict__ lin2,
    const float* __restrict__ linw,
    u16* __restrict__ lin1T, u16* __restrict__ lin2T, u16* __restrict__ linwT,
    int N, int E)
{
    __shared__ K1Smem sm;

    const int tid = threadIdx.x;
    const int b   = blockIdx.x;

    if (b < TBLB) {
        const int s0 = b * TSPB;
        const float TSTEP = TMAXD / TN;
        const float GSTEP = 10.0f / 49.0f;
        const float COEFF = -0.5f / (GSTEP * GSTEP);

        for (int idx = tid; idx < TSPB * 64; idx += 256) {
            int s = idx >> 6, g = idx & 63;
            float v = 0.f;
            if (g < NG) {
                float d = (float)(s0 + s) * TSTEP;
                float t = d - (float)g * GSTEP;
                v = __expf(COEFF * t * t);
            }
            sm.tb.sattr[s][g] = v;
        }
        __syncthreads();

        const int c  = tid & 127;
        const int sh = tid >> 7;

        for (int s = sh; s < TSPB; s += 2) {
            float acc = b1[c];
#pragma unroll
            for (int g = 0; g < NG; ++g)
                acc = fmaf(sm.tb.sattr[s][g], w1[g * 128 + c], acc);
            sm.tb.st1[s][c] = sspf(acc);
        }
        __syncthreads();

        for (int s = sh; s < TSPB; s += 2) {
            float acc = b2[c];
#pragma unroll 8
            for (int k = 0; k < 128; ++k)
                acc = fmaf(sm.tb.st1[s][k], w2[k * 128 + c], acc);
            float d = (float)(s0 + s) * TSTEP;
            float Cf = 0.5f * (__cosf(d * 0.31415926535f) + 1.0f);
            Tn[(size_t)(s0 + s) * HID + c] = f2bf(acc * Cf);
        }
    } else if (b < TBLB + NRG * NSL) {
        int* hcnt = sm.hcnt;
        const int hb  = b - TBLB;
        const int rg  = hb / NSL;
        const int sl  = hb % NSL;
        const int rph = (N + NRG - 1) / NRG;
        const int lo  = rg * rph;
        const int hi  = min(lo + rph, N);
        const int nr  = hi - lo;

        for (int i = tid; i < nr; i += 256) hcnt[i] = 0;
        __syncthreads();

        const int esz = (E / NSL) & ~3;
        const int es  = sl * esz;
        const int ee  = (sl == NSL - 1) ? E : es + esz;
        const int n4  = (ee - es) >> 2;
        const i32x4* p4 = reinterpret_cast<const i32x4*>(eidx + es);
        for (int i = tid; i < n4; i += 256) {
            i32x4 v = p4[i];
#pragma unroll
            for (int j = 0; j < 4; ++j) {
                u32 rr = (u32)(v[j] - lo);
                if (rr < (u32)nr) atomicAdd(&hcnt[rr], 1);
            }
        }
        for (int e = es + (n4 << 2) + tid; e < ee; e += 256) {
            u32 rr = (u32)(eidx[e] - lo);
            if (rr < (u32)nr) atomicAdd(&hcnt[rr], 1);
        }
        __syncthreads();

        for (int i = tid; i < nr; i += 256)
            cntp[(size_t)sl * N + lo + i] = hcnt[i];
    } else if (b < TBLB + NRG * NSL + 192) {
        const int wt  = b - TBLB - NRG * NSL;
        const int wid = wt >> 6;
        const int t   = (wt & 63) * 256 + tid;
        const int n = t >> 7, k = t & 127;
        const float* src = (wid == 0) ? lin1 : (wid == 1) ? lin2 : linw;
        u16* dst = (wid == 0) ? lin1T : (wid == 1) ? lin2T : linwT;
        dst[t] = f2bf(src[k * 128 + n]);
    } else {
        const int rb = b - TBLB - NRG * NSL - 192;
        const int e  = rb * 256 + tid;
        if (e < E) {
            int r = eidx[e], c = eidx[E + e];
            float dx = pos[3 * r + 0] - pos[3 * c + 0];
            float dy = pos[3 * r + 1] - pos[3 * c + 1];
            float dz = pos[3 * r + 2] - pos[3 * c + 2];
            float d = sqrtf(dx * dx + dy * dy + dz * dz);
            int idx = (int)(d * (TN / TMAXD) + 0.5f);
            idx = min(idx, TN - 1);
            rec[e] = ((u32)idx << 16) | (u32)c;
        }
    }
}

// ===========================================================================
// K2: [0,nch) fold cntp->cnt + in-place exclusive slice prefix | MFMA GEMM
// ===========================================================================
__global__ __launch_bounds__(256) void k2_part_mfma(
    int* __restrict__ cntp, int* __restrict__ cnt, int* __restrict__ part,
    int nch,
    const float* __restrict__ h, const u16* __restrict__ lin1T,
    u16* __restrict__ bx, int N)
{
    __shared__ u16 sA[64 * 128];
    __shared__ int red[256];
    const int tid = threadIdx.x;

    if ((int)blockIdx.x < nch) {
        const int b = blockIdx.x;
        int base = b * SCAN_CHUNK + tid * 4;
        int s = 0;
#pragma unroll
        for (int i = 0; i < 4; ++i) {
            int idx = base + i;
            if (idx < N) {
                int run = 0;
#pragma unroll
                for (int sl = 0; sl < NSL; ++sl) {
                    int v = cntp[(size_t)sl * N + idx];
                    cntp[(size_t)sl * N + idx] = run;
                    run += v;
                }
                cnt[idx] = run;
                s += run;
            }
        }
        red[tid] = s;
        __syncthreads();
        for (int off = 128; off > 0; off >>= 1) {
            if (tid < off) red[tid] += red[tid + off];
            __syncthreads();
        }
        if (tid == 0) part[b] = red[0];
        return;
    }

    const int r0 = ((int)blockIdx.x - nch) * 64;

    for (int i = tid; i < 64 * 16; i += 256) {
        int row = i >> 4, ck = i & 15;
        i32x4 pk = (i32x4){0, 0, 0, 0};
        if (r0 + row < N) {
            const float* src = h + (size_t)(r0 + row) * HID + ck * 8;
            f32x4 a = *reinterpret_cast<const f32x4*>(src);
            f32x4 c = *reinterpret_cast<const f32x4*>(src + 4);
            pk[0] = (int)((u32)f2bf(a[0]) | ((u32)f2bf(a[1]) << 16));
            pk[1] = (int)((u32)f2bf(a[2]) | ((u32)f2bf(a[3]) << 16));
            pk[2] = (int)((u32)f2bf(c[0]) | ((u32)f2bf(c[1]) << 16));
            pk[3] = (int)((u32)f2bf(c[2]) | ((u32)f2bf(c[3]) << 16));
        }
        int byteoff = row * 256 + ((ck * 16) ^ ((row & 7) << 4));
        *reinterpret_cast<i32x4*>(reinterpret_cast<char*>(sA) + byteoff) = pk;
    }
    __syncthreads();

    const int lane = tid & 63;
    const int wv   = tid >> 6;
    const int l15  = lane & 15;
    const int l4   = lane >> 4;

    bf16x8 bw[2][4];
#pragma unroll
    for (int nt = 0; nt < 2; ++nt)
#pragma unroll
        for (int s = 0; s < 4; ++s) {
            int n = wv * 32 + nt * 16 + l15;
            bw[nt][s] = *reinterpret_cast<const bf16x8*>(lin1T + n * 128 + s * 32 + l4 * 8);
        }

    f32x4 acc[4][2];
#pragma unroll
    for (int mt = 0; mt < 4; ++mt) { acc[mt][0] = (f32x4){0,0,0,0}; acc[mt][1] = (f32x4){0,0,0,0}; }

#pragma unroll
    for (int mt = 0; mt < 4; ++mt)
#pragma unroll
        for (int s = 0; s < 4; ++s) {
            int e = mt * 16 + l15;
            int byteoff = e * 256 + ((s * 64 + l4 * 16) ^ ((e & 7) << 4));
            bf16x8 af = *reinterpret_cast<const bf16x8*>(reinterpret_cast<char*>(sA) + byteoff);
            acc[mt][0] = __builtin_amdgcn_mfma_f32_16x16x32_bf16(af, bw[0][s], acc[mt][0], 0, 0, 0);
            acc[mt][1] = __builtin_amdgcn_mfma_f32_16x16x32_bf16(af, bw[1][s], acc[mt][1], 0, 0, 0);
        }

#pragma unroll
    for (int mt = 0; mt < 4; ++mt)
#pragma unroll
        for (int nt = 0; nt < 2; ++nt)
#pragma unroll
            for (int r = 0; r < 4; ++r) {
                int row = r0 + mt * 16 + l4 * 4 + r;
                if (row < N)
                    bx[(size_t)row * HID + wv * 32 + nt * 16 + l15] = f2bf(acc[mt][nt][r]);
            }
}

// ===========================================================================
// K3: scan phase 2 — cur[r] = exclusive prefix (row START offsets)
// ===========================================================================
__global__ __launch_bounds__(256) void scan_write(
    const int* __restrict__ cnt, const int* __restrict__ part,
    int* __restrict__ cur, int N)
{
    __shared__ int sc[256];
    int b = blockIdx.x, tid = threadIdx.x;
    int base = 0;
    for (int i = 0; i < b; ++i) base += part[i];
    int gbase = b * SCAN_CHUNK + tid * 4;
    int v[4];
#pragma unroll
    for (int i = 0; i < 4; ++i) { int idx = gbase + i; v[i] = (idx < N) ? cnt[idx] : 0; }
    int tsum = v[0] + v[1] + v[2] + v[3];
    sc[tid] = tsum;
    __syncthreads();
    for (int off = 1; off < 256; off <<= 1) {
        int add = (tid >= off) ? sc[tid - off] : 0;
        __syncthreads();
        sc[tid] += add;
        __syncthreads();
    }
    int tpre = base + sc[tid] - tsum;
    int run = 0;
#pragma unroll
    for (int i = 0; i < 4; ++i) {
        int idx = gbase + i;
        if (idx < N) cur[idx] = tpre + run;
        run += v[i];
    }
}

// ===========================================================================
// K4: scatter_sorted — zero global atomics.
// ===========================================================================
__global__ __launch_bounds__(256) void scatter_sorted(
    const int* __restrict__ eidx, const u32* __restrict__ rec,
    const int* __restrict__ cur, const int* __restrict__ cntp,
    u32* __restrict__ ec, int N, int E)
{
    __shared__ int lbase[3328];
    __shared__ int lcnt[3328];
    const int tid = threadIdx.x;
    const int rg  = blockIdx.x / NSL;
    const int sl  = blockIdx.x % NSL;
    const int rph = (N + NRG - 1) / NRG;
    const int lo  = rg * rph;
    const int hi  = min(lo + rph, N);
    const int nr  = hi - lo;

    for (int i = tid; i < nr; i += 256) {
        lbase[i] = cur[lo + i] + cntp[(size_t)sl * N + lo + i];
        lcnt[i]  = 0;
    }
    __syncthreads();

    const int esz = (E / NSL) & ~3;
    const int es  = sl * esz;
    const int ee  = (sl == NSL - 1) ? E : es + esz;
    const int n4  = (ee - es) >> 2;
    const i32x4* p4 = reinterpret_cast<const i32x4*>(eidx + es);
    for (int i = tid; i < n4; i += 256) {
        i32x4 v = p4[i];
#pragma unroll
        for (int j = 0; j < 4; ++j) {
            u32 rr = (u32)(v[j] - lo);
            if (rr < (u32)nr) {
                int o = atomicAdd(&lcnt[rr], 1);
                ec[lbase[rr] + o] = rec[es + (i << 2) + j];
            }
        }
    }
    for (int e = es + (n4 << 2) + tid; e < ee; e += 256) {
        u32 rr = (u32)(eidx[e] - lo);
        if (rr < (u32)nr) {
            int o = atomicAdd(&lcnt[rr], 1);
            ec[lbase[rr] + o] = rec[e];
        }
    }
}

// ===========================================================================
// FUSED edge gather + tail MLP: 16-row tiles (3125 blocks).
// Phase 1: 4 waves x 4 rows, R11 pair loops, results -> swizzled bf16 LDS
//          (bit-identical to prior agg->bf16 staging).
// Phase 2: GEMM1 ssp -> same LDS (barrier-unioned) -> GEMM2 -> out.
// ===========================================================================
__device__ __forceinline__ void eload4(
    const u32 v[4], const u16* __restrict__ Tn, const u16* __restrict__ bx,
    int c2, u32 T[4], u32 X[4])
{
#pragma unroll
    for (int j = 0; j < 4; ++j) {
        u32 rv = (u32)__builtin_amdgcn_readfirstlane((int)v[j]);
        int is = (int)(rv >> 16);
        int cs = (int)(rv & 0xffffu);
        T[j] = *reinterpret_cast<const u32*>(Tn + (size_t)is * HID + c2);
        X[j] = *reinterpret_cast<const u32*>(bx + (size_t)cs * HID + c2);
    }
}

__device__ __forceinline__ void efma4(
    const u32 T[4], const u32 X[4], float& ax, float& ay)
{
#pragma unroll
    for (int j = 0; j < 4; ++j) {
        ax = fmaf(bf2f(T[j] & 0xffffu), bf2f(X[j] & 0xffffu), ax);
        ay = fmaf(bf2f(T[j] >> 16), bf2f(X[j] >> 16), ay);
    }
}

__device__ __forceinline__ void eone(
    u32 v0, const u16* __restrict__ Tn, const u16* __restrict__ bx,
    int c2, float& ax, float& ay)
{
    u32 rv = (u32)__builtin_amdgcn_readfirstlane((int)v0);
    int is = (int)(rv >> 16);
    int cs = (int)(rv & 0xffffu);
    u32 T0 = *reinterpret_cast<const u32*>(Tn + (size_t)is * HID + c2);
    u32 X0 = *reinterpret_cast<const u32*>(bx + (size_t)cs * HID + c2);
    ax = fmaf(bf2f(T0 & 0xffffu), bf2f(X0 & 0xffffu), ax);
    ay = fmaf(bf2f(T0 >> 16), bf2f(X0 >> 16), ay);
}

__global__ __launch_bounds__(256) void edge_tail(
    const int* __restrict__ rowstart,
    const u32* __restrict__ ec,
    const u16* __restrict__ Tn,
    const u16* __restrict__ bx,
    const u16* __restrict__ lin2T, const float* __restrict__ l2b,
    const u16* __restrict__ linwT, const float* __restrict__ linb,
    float*     __restrict__ out,
    int N, int E)
{
    __shared__ u16 sA[16 * 128];   // 4 KB; gather results, then t (time-union)

    const int lane = threadIdx.x & 63;
    const int wv   = threadIdx.x >> 6;      // wave = slot = col group
    const int c2   = lane * 2;
    const int r0   = blockIdx.x * 16;

    // ---- phase 1: gather 4 rows per wave (two pair loops) ------------------
#pragma unroll
    for (int pp = 0; pp < 2; ++pp) {
        const int mA = wv * 4 + pp * 2;
        const int mB = mA + 1;
        const int rA = r0 + mA;
        const int rB = r0 + mB;

        int eA = 0, eeA = 0, eB = 0, eeB = 0;
        if (rA < N) { eA = rowstart[rA]; eeA = (rA == N - 1) ? E : rowstart[rA + 1]; }
        if (rB < N) { eB = rowstart[rB]; eeB = (rB == N - 1) ? E : rowstart[rB + 1]; }

        float axA = 0.f, ayA = 0.f, axB = 0.f, ayB = 0.f;
        u32 vA[4], vB[4], TA[4], TB[4], XA[4], XB[4];

        while (eA + 4 <= eeA && eB + 4 <= eeB) {
#pragma unroll
            for (int j = 0; j < 4; ++j) { vA[j] = ec[eA + j]; vB[j] = ec[eB + j]; }
            eload4(vA, Tn, bx, c2, TA, XA);
            eload4(vB, Tn, bx, c2, TB, XB);
            efma4(TA, XA, axA, ayA);
            efma4(TB, XB, axB, ayB);
            eA += 4; eB += 4;
        }
        while (eA + 4 <= eeA) {
#pragma unroll
            for (int j = 0; j < 4; ++j) vA[j] = ec[eA + j];
            eload4(vA, Tn, bx, c2, TA, XA);
            efma4(TA, XA, axA, ayA);
            eA += 4;
        }
        for (; eA < eeA; ++eA) eone(ec[eA], Tn, bx, c2, axA, ayA);
        while (eB + 4 <= eeB) {
#pragma unroll
            for (int j = 0; j < 4; ++j) vB[j] = ec[eB + j];
            eload4(vB, Tn, bx, c2, TB, XB);
            efma4(TB, XB, axB, ayB);
            eB += 4;
        }
        for (; eB < eeB; ++eB) eone(ec[eB], Tn, bx, c2, axB, ayB);

        // store both rows as bf16 pairs into swizzled staging LDS
        u32 pA = (u32)f2bf(axA) | ((u32)f2bf(ayA) << 16);
        u32 pB = (u32)f2bf(axB) | ((u32)f2bf(ayB) << 16);
        int boA = mA * 256 + ((c2 * 2) ^ ((mA & 7) << 4));
        int boB = mB * 256 + ((c2 * 2) ^ ((mB & 7) << 4));
        *reinterpret_cast<u32*>(reinterpret_cast<char*>(sA) + boA) = pA;
        *reinterpret_cast<u32*>(reinterpret_cast<char*>(sA) + boB) = pB;
    }
    __syncthreads();

    // ---- phase 2: tail MLP (M=16) ------------------------------------------
    const int l15 = lane & 15;
    const int l4  = lane >> 4;
    const int n0  = wv * 32 + l15;
    const int n1  = n0 + 16;

    // GEMM1: t = ssp(A @ lin2 + l2b)
    f32x4 acc0 = (f32x4){0, 0, 0, 0};
    f32x4 acc1 = (f32x4){0, 0, 0, 0};
    {
        bf16x8 bw[2][4];
#pragma unroll
        for (int nt = 0; nt < 2; ++nt)
#pragma unroll
            for (int s = 0; s < 4; ++s) {
                int n = wv * 32 + nt * 16 + l15;
                bw[nt][s] = *reinterpret_cast<const bf16x8*>(lin2T + n * 128 + s * 32 + l4 * 8);
            }
#pragma unroll
        for (int s = 0; s < 4; ++s) {
            int e = l15;
            int byteoff = e * 256 + ((s * 64 + l4 * 16) ^ ((e & 7) << 4));
            bf16x8 af = *reinterpret_cast<const bf16x8*>(reinterpret_cast<char*>(sA) + byteoff);
            acc0 = __builtin_amdgcn_mfma_f32_16x16x32_bf16(af, bw[0][s], acc0, 0, 0, 0);
            acc1 = __builtin_amdgcn_mfma_f32_16x16x32_bf16(af, bw[1][s], acc1, 0, 0, 0);
        }
    }
    __syncthreads();   // all sA reads complete before overwrite

    {
        const float bb0 = l2b[n0];
        const float bb1 = l2b[n1];
#pragma unroll
        for (int r = 0; r < 4; ++r) {
            int m = l4 * 4 + r;
            float v0 = sspf(acc0[r] + bb0);
            float v1 = sspf(acc1[r] + bb1);
            int bo0 = m * 256 + ((n0 * 2) ^ ((m & 7) << 4));
            int bo1 = m * 256 + ((n1 * 2) ^ ((m & 7) << 4));
            *reinterpret_cast<u16*>(reinterpret_cast<char*>(sA) + bo0) = f2bf(v0);
            *reinterpret_cast<u16*>(reinterpret_cast<char*>(sA) + bo1) = f2bf(v1);
        }
    }
    __syncthreads();

    // GEMM2: out = t @ lin_w + lin_b
    acc0 = (f32x4){0, 0, 0, 0};
    acc1 = (f32x4){0, 0, 0, 0};
    {
        bf16x8 bw[2][4];
#pragma unroll
        for (int nt = 0; nt < 2; ++nt)
#pragma unroll
            for (int s = 0; s < 4; ++s) {
                int n = wv * 32 + nt * 16 + l15;
                bw[nt][s] = *reinterpret_cast<const bf16x8*>(linwT + n * 128 + s * 32 + l4 * 8);
            }
#pragma unroll
        for (int s = 0; s < 4; ++s) {
            int e = l15;
            int byteoff = e * 256 + ((s * 64 + l4 * 16) ^ ((e & 7) << 4));
            bf16x8 af = *reinterpret_cast<const bf16x8*>(reinterpret_cast<char*>(sA) + byteoff);
            acc0 = __builtin_amdgcn_mfma_f32_16x16x32_bf16(af, bw[0][s], acc0, 0, 0, 0);
            acc1 = __builtin_amdgcn_mfma_f32_16x16x32_bf16(af, bw[1][s], acc1, 0, 0, 0);
        }
    }
    {
        const float cb0 = linb[n0];
        const float cb1 = linb[n1];
#pragma unroll
        for (int r = 0; r < 4; ++r) {
            int row = r0 + l4 * 4 + r;
            if (row < N) {
                out[(size_t)row * HID + n0] = acc0[r] + cb0;
                out[(size_t)row * HID + n1] = acc1[r] + cb1;
            }
        }
    }
}

// ===========================================================================
extern "C" void kernel_launch(void* const* d_in, const int* in_sizes, int n_in,
                              void* d_out, int out_size, void* d_ws, size_t ws_size,
                              hipStream_t stream)
{
    const float* h    = (const float*)d_in[0];
    const float* pos  = (const float*)d_in[1];
    const int*   eidx = (const int*)  d_in[2];
    const float* w1   = (const float*)d_in[3];
    const float* b1   = (const float*)d_in[4];
    const float* w2   = (const float*)d_in[5];
    const float* b2   = (const float*)d_in[6];
    const float* lin1 = (const float*)d_in[7];
    const float* lin2 = (const float*)d_in[8];
    const float* l2b  = (const float*)d_in[9];
    const float* linw = (const float*)d_in[10];
    const float* linb = (const float*)d_in[11];

    const int N = in_sizes[0] / HID;
    const int E = in_sizes[2] / 2;

    char* ws = (char*)d_ws;
    size_t off = 0;
    auto alloc = [&](size_t bytes) { char* p = ws + off; off = (off + bytes + 255) & ~(size_t)255; return p; };

    u16*    bx    = (u16*)   alloc((size_t)N * HID * sizeof(u16));
    u16*    Tn    = (u16*)   alloc((size_t)TN * HID * sizeof(u16));
    int*    cntp  = (int*)   alloc((size_t)NSL * N * sizeof(int));
    int*    cnt   = (int*)   alloc((size_t)N * sizeof(int));
    int*    cur   = (int*)   alloc((size_t)N * sizeof(int));
    int*    part  = (int*)   alloc(256 * sizeof(int));
    u32*    rec   = (u32*)   alloc((size_t)E * sizeof(u32));
    u32*    ec    = (u32*)   alloc(((size_t)E + 8) * sizeof(u32));
    u16*    lin1T = (u16*)   alloc(128 * 128 * sizeof(u16));
    u16*    lin2T = (u16*)   alloc(128 * 128 * sizeof(u16));
    u16*    linwT = (u16*)   alloc(128 * 128 * sizeof(u16));

    const int nrec = (E + 255) / 256;

    // K1: table + hist + transposes + rec (no global atomics anywhere)
    k1_table_hist_prep<<<TBLB + NRG * NSL + 192 + nrec, 256, 0, stream>>>(
        w1, b1, w2, b2, Tn, eidx, cntp, pos, rec,
        lin1, lin2, linw, lin1T, lin2T, linwT, N, E);

    // K2: fold cntp -> cnt (+ in-place slice prefix) || MFMA node GEMM
    const int nch = (N + SCAN_CHUNK - 1) / SCAN_CHUNK;
    const int ngb = (N + 63) / 64;
    k2_part_mfma<<<nch + ngb, 256, 0, stream>>>(cntp, cnt, part, nch, h, lin1T, bx, N);

    // K3: scan phase 2 -> cur (row START offsets)
    scan_write<<<nch, 256, 0, stream>>>(cnt, part, cur, N);

    // K4: deterministic-offset scatter, zero global atomics
    scatter_sorted<<<NRG * NSL, 256, 0, stream>>>(eidx, rec, cur, cntp, ec, N, E);

    // FUSED: edge gather + tail MLP -> out (16-row tiles, no agg buffer)
    const int ntile = (N + 15) / 16;
    edge_tail<<<ntile, 256, 0, stream>>>(cur, ec, Tn, bx,
                                         lin2T, l2b, linwT, linb,
                                         (float*)d_out, N, E);
}

// Round 20
// 150.604 us; speedup vs baseline: 1.0325x; 1.0325x over previous
//
#include <hip/hip_runtime.h>
#include <hip/hip_bf16.h>
#include <math.h>

#define HID   128
#define NG    50
#define TN    8192          // table entries (nearest-neighbor lookup)
#define TMAXD 16.0f         // table covers d in [0, 16)
#define RPB   8             // rows per block in CSR kernel (4 slots x 2 rows/wave)
#define TSPB  16            // samples per block in table branch
#define TBLB  512           // table blocks (TN / TSPB)
#define NRG   16            // hist/scatter row-ranges
#define NSL   32            // hist/scatter edge-slices (NRG*NSL = 512 blocks)
#define SCAN_CHUNK 1024

typedef __attribute__((ext_vector_type(8))) short bf16x8;
typedef __attribute__((ext_vector_type(4))) float f32x4;
typedef __attribute__((ext_vector_type(4))) int   i32x4;
typedef unsigned short u16;
typedef unsigned int   u32;

#define LOG2F 0.69314718056f

__device__ __forceinline__ float sspf(float v) {
    if (v > 15.f) return v - LOG2F;
    return __logf(1.f + __expf(v)) - LOG2F;
}

__device__ __forceinline__ u16 f2bf(float f) {
    __hip_bfloat16 h = __float2bfloat16(f);
    return *reinterpret_cast<u16*>(&h);
}
__device__ __forceinline__ float bf2f(u32 v) {
    union { u32 u; float f; } x; x.u = v << 16; return x.f;
}

union K1Smem {
    struct { float sattr[TSPB][64]; float st1[TSPB][128]; } tb;   // 12 KB
    int hcnt[3328];                                               // 13.3 KB
};

// ===========================================================================
// K1: [0,TBLB) table | [+512) 2-D hist (LDS atomics) | [+192) transposes |
//     [+nrec) rec[e] = (tbl_idx<<16)|col, coalesced, no atomics
// ===========================================================================
__global__ __launch_bounds__(256) void k1_table_hist_prep(
    const float* __restrict__ w1, const float* __restrict__ b1,
    const float* __restrict__ w2, const float* __restrict__ b2,
    u16* __restrict__ Tn,
    const int* __restrict__ eidx, int* __restrict__ cntp,   // [NSL][N]
    const float* __restrict__ pos, u32* __restrict__ rec,
    const float* __restrict__ lin1, const float* __restrict__ lin2,
    const float* __restrict__ linw,
    u16* __restrict__ lin1T, u16* __restrict__ lin2T, u16* __restrict__ linwT,
    int N, int E)
{
    __shared__ K1Smem sm;

    const int tid = threadIdx.x;
    const int b   = blockIdx.x;

    if (b < TBLB) {
        const int s0 = b * TSPB;
        const float TSTEP = TMAXD / TN;
        const float GSTEP = 10.0f / 49.0f;
        const float COEFF = -0.5f / (GSTEP * GSTEP);

        for (int idx = tid; idx < TSPB * 64; idx += 256) {
            int s = idx >> 6, g = idx & 63;
            float v = 0.f;
            if (g < NG) {
                float d = (float)(s0 + s) * TSTEP;
                float t = d - (float)g * GSTEP;
                v = __expf(COEFF * t * t);
            }
            sm.tb.sattr[s][g] = v;
        }
        __syncthreads();

        const int c  = tid & 127;
        const int sh = tid >> 7;

        for (int s = sh; s < TSPB; s += 2) {
            float acc = b1[c];
#pragma unroll
            for (int g = 0; g < NG; ++g)
                acc = fmaf(sm.tb.sattr[s][g], w1[g * 128 + c], acc);
            sm.tb.st1[s][c] = sspf(acc);
        }
        __syncthreads();

        for (int s = sh; s < TSPB; s += 2) {
            float acc = b2[c];
#pragma unroll 8
            for (int k = 0; k < 128; ++k)
                acc = fmaf(sm.tb.st1[s][k], w2[k * 128 + c], acc);
            float d = (float)(s0 + s) * TSTEP;
            float Cf = 0.5f * (__cosf(d * 0.31415926535f) + 1.0f);
            Tn[(size_t)(s0 + s) * HID + c] = f2bf(acc * Cf);
        }
    } else if (b < TBLB + NRG * NSL) {
        int* hcnt = sm.hcnt;
        const int hb  = b - TBLB;
        const int rg  = hb / NSL;
        const int sl  = hb % NSL;
        const int rph = (N + NRG - 1) / NRG;
        const int lo  = rg * rph;
        const int hi  = min(lo + rph, N);
        const int nr  = hi - lo;

        for (int i = tid; i < nr; i += 256) hcnt[i] = 0;
        __syncthreads();

        const int esz = (E / NSL) & ~3;
        const int es  = sl * esz;
        const int ee  = (sl == NSL - 1) ? E : es + esz;
        const int n4  = (ee - es) >> 2;
        const i32x4* p4 = reinterpret_cast<const i32x4*>(eidx + es);
        for (int i = tid; i < n4; i += 256) {
            i32x4 v = p4[i];
#pragma unroll
            for (int j = 0; j < 4; ++j) {
                u32 rr = (u32)(v[j] - lo);
                if (rr < (u32)nr) atomicAdd(&hcnt[rr], 1);
            }
        }
        for (int e = es + (n4 << 2) + tid; e < ee; e += 256) {
            u32 rr = (u32)(eidx[e] - lo);
            if (rr < (u32)nr) atomicAdd(&hcnt[rr], 1);
        }
        __syncthreads();

        for (int i = tid; i < nr; i += 256)
            cntp[(size_t)sl * N + lo + i] = hcnt[i];
    } else if (b < TBLB + NRG * NSL + 192) {
        const int wt  = b - TBLB - NRG * NSL;
        const int wid = wt >> 6;
        const int t   = (wt & 63) * 256 + tid;
        const int n = t >> 7, k = t & 127;
        const float* src = (wid == 0) ? lin1 : (wid == 1) ? lin2 : linw;
        u16* dst = (wid == 0) ? lin1T : (wid == 1) ? lin2T : linwT;
        dst[t] = f2bf(src[k * 128 + n]);
    } else {
        const int rb = b - TBLB - NRG * NSL - 192;
        const int e  = rb * 256 + tid;
        if (e < E) {
            int r = eidx[e], c = eidx[E + e];
            float dx = pos[3 * r + 0] - pos[3 * c + 0];
            float dy = pos[3 * r + 1] - pos[3 * c + 1];
            float dz = pos[3 * r + 2] - pos[3 * c + 2];
            float d = sqrtf(dx * dx + dy * dy + dz * dz);
            int idx = (int)(d * (TN / TMAXD) + 0.5f);
            idx = min(idx, TN - 1);
            rec[e] = ((u32)idx << 16) | (u32)c;
        }
    }
}

// ===========================================================================
// K2: [0,nch) fold cntp->cnt + in-place exclusive slice prefix | MFMA GEMM
// ===========================================================================
__global__ __launch_bounds__(256) void k2_part_mfma(
    int* __restrict__ cntp, int* __restrict__ cnt, int* __restrict__ part,
    int nch,
    const float* __restrict__ h, const u16* __restrict__ lin1T,
    u16* __restrict__ bx, int N)
{
    __shared__ u16 sA[64 * 128];
    __shared__ int red[256];
    const int tid = threadIdx.x;

    if ((int)blockIdx.x < nch) {
        const int b = blockIdx.x;
        int base = b * SCAN_CHUNK + tid * 4;
        int s = 0;
#pragma unroll
        for (int i = 0; i < 4; ++i) {
            int idx = base + i;
            if (idx < N) {
                int run = 0;
#pragma unroll
                for (int sl = 0; sl < NSL; ++sl) {
                    int v = cntp[(size_t)sl * N + idx];
                    cntp[(size_t)sl * N + idx] = run;
                    run += v;
                }
                cnt[idx] = run;
                s += run;
            }
        }
        red[tid] = s;
        __syncthreads();
        for (int off = 128; off > 0; off >>= 1) {
            if (tid < off) red[tid] += red[tid + off];
            __syncthreads();
        }
        if (tid == 0) part[b] = red[0];
        return;
    }

    const int r0 = ((int)blockIdx.x - nch) * 64;

    for (int i = tid; i < 64 * 16; i += 256) {
        int row = i >> 4, ck = i & 15;
        i32x4 pk = (i32x4){0, 0, 0, 0};
        if (r0 + row < N) {
            const float* src = h + (size_t)(r0 + row) * HID + ck * 8;
            f32x4 a = *reinterpret_cast<const f32x4*>(src);
            f32x4 c = *reinterpret_cast<const f32x4*>(src + 4);
            pk[0] = (int)((u32)f2bf(a[0]) | ((u32)f2bf(a[1]) << 16));
            pk[1] = (int)((u32)f2bf(a[2]) | ((u32)f2bf(a[3]) << 16));
            pk[2] = (int)((u32)f2bf(c[0]) | ((u32)f2bf(c[1]) << 16));
            pk[3] = (int)((u32)f2bf(c[2]) | ((u32)f2bf(c[3]) << 16));
        }
        int byteoff = row * 256 + ((ck * 16) ^ ((row & 7) << 4));
        *reinterpret_cast<i32x4*>(reinterpret_cast<char*>(sA) + byteoff) = pk;
    }
    __syncthreads();

    const int lane = tid & 63;
    const int wv   = tid >> 6;
    const int l15  = lane & 15;
    const int l4   = lane >> 4;

    bf16x8 bw[2][4];
#pragma unroll
    for (int nt = 0; nt < 2; ++nt)
#pragma unroll
        for (int s = 0; s < 4; ++s) {
            int n = wv * 32 + nt * 16 + l15;
            bw[nt][s] = *reinterpret_cast<const bf16x8*>(lin1T + n * 128 + s * 32 + l4 * 8);
        }

    f32x4 acc[4][2];
#pragma unroll
    for (int mt = 0; mt < 4; ++mt) { acc[mt][0] = (f32x4){0,0,0,0}; acc[mt][1] = (f32x4){0,0,0,0}; }

#pragma unroll
    for (int mt = 0; mt < 4; ++mt)
#pragma unroll
        for (int s = 0; s < 4; ++s) {
            int e = mt * 16 + l15;
            int byteoff = e * 256 + ((s * 64 + l4 * 16) ^ ((e & 7) << 4));
            bf16x8 af = *reinterpret_cast<const bf16x8*>(reinterpret_cast<char*>(sA) + byteoff);
            acc[mt][0] = __builtin_amdgcn_mfma_f32_16x16x32_bf16(af, bw[0][s], acc[mt][0], 0, 0, 0);
            acc[mt][1] = __builtin_amdgcn_mfma_f32_16x16x32_bf16(af, bw[1][s], acc[mt][1], 0, 0, 0);
        }

#pragma unroll
    for (int mt = 0; mt < 4; ++mt)
#pragma unroll
        for (int nt = 0; nt < 2; ++nt)
#pragma unroll
            for (int r = 0; r < 4; ++r) {
                int row = r0 + mt * 16 + l4 * 4 + r;
                if (row < N)
                    bx[(size_t)row * HID + wv * 32 + nt * 16 + l15] = f2bf(acc[mt][nt][r]);
            }
}

// ===========================================================================
// K3: scan phase 2 — cur[r] = exclusive prefix (row START offsets)
// ===========================================================================
__global__ __launch_bounds__(256) void scan_write(
    const int* __restrict__ cnt, const int* __restrict__ part,
    int* __restrict__ cur, int N)
{
    __shared__ int sc[256];
    int b = blockIdx.x, tid = threadIdx.x;
    int base = 0;
    for (int i = 0; i < b; ++i) base += part[i];
    int gbase = b * SCAN_CHUNK + tid * 4;
    int v[4];
#pragma unroll
    for (int i = 0; i < 4; ++i) { int idx = gbase + i; v[i] = (idx < N) ? cnt[idx] : 0; }
    int tsum = v[0] + v[1] + v[2] + v[3];
    sc[tid] = tsum;
    __syncthreads();
    for (int off = 1; off < 256; off <<= 1) {
        int add = (tid >= off) ? sc[tid - off] : 0;
        __syncthreads();
        sc[tid] += add;
        __syncthreads();
    }
    int tpre = base + sc[tid] - tsum;
    int run = 0;
#pragma unroll
    for (int i = 0; i < 4; ++i) {
        int idx = gbase + i;
        if (idx < N) cur[idx] = tpre + run;
        run += v[i];
    }
}

// ===========================================================================
// K4: scatter_sorted — zero global atomics.
// ===========================================================================
__global__ __launch_bounds__(256) void scatter_sorted(
    const int* __restrict__ eidx, const u32* __restrict__ rec,
    const int* __restrict__ cur, const int* __restrict__ cntp,
    u32* __restrict__ ec, int N, int E)
{
    __shared__ int lbase[3328];
    __shared__ int lcnt[3328];
    const int tid = threadIdx.x;
    const int rg  = blockIdx.x / NSL;
    const int sl  = blockIdx.x % NSL;
    const int rph = (N + NRG - 1) / NRG;
    const int lo  = rg * rph;
    const int hi  = min(lo + rph, N);
    const int nr  = hi - lo;

    for (int i = tid; i < nr; i += 256) {
        lbase[i] = cur[lo + i] + cntp[(size_t)sl * N + lo + i];
        lcnt[i]  = 0;
    }
    __syncthreads();

    const int esz = (E / NSL) & ~3;
    const int es  = sl * esz;
    const int ee  = (sl == NSL - 1) ? E : es + esz;
    const int n4  = (ee - es) >> 2;
    const i32x4* p4 = reinterpret_cast<const i32x4*>(eidx + es);
    for (int i = tid; i < n4; i += 256) {
        i32x4 v = p4[i];
#pragma unroll
        for (int j = 0; j < 4; ++j) {
            u32 rr = (u32)(v[j] - lo);
            if (rr < (u32)nr) {
                int o = atomicAdd(&lcnt[rr], 1);
                ec[lbase[rr] + o] = rec[es + (i << 2) + j];
            }
        }
    }
    for (int e = es + (n4 << 2) + tid; e < ee; e += 256) {
        u32 rr = (u32)(eidx[e] - lo);
        if (rr < (u32)nr) {
            int o = atomicAdd(&lcnt[rr], 1);
            ec[lbase[rr] + o] = rec[e];
        }
    }
}

// ===========================================================================
// CSR message passing: rowstart = cur[r] (exclusive scan), end = cur[r+1]|E
// ===========================================================================
__device__ __forceinline__ void eload4(
    const u32 v[4], const u16* __restrict__ Tn, const u16* __restrict__ bx,
    int c2, u32 T[4], u32 X[4])
{
#pragma unroll
    for (int j = 0; j < 4; ++j) {
        u32 rv = (u32)__builtin_amdgcn_readfirstlane((int)v[j]);
        int is = (int)(rv >> 16);
        int cs = (int)(rv & 0xffffu);
        T[j] = *reinterpret_cast<const u32*>(Tn + (size_t)is * HID + c2);
        X[j] = *reinterpret_cast<const u32*>(bx + (size_t)cs * HID + c2);
    }
}

__device__ __forceinline__ void efma4(
    const u32 T[4], const u32 X[4], float& ax, float& ay)
{
#pragma unroll
    for (int j = 0; j < 4; ++j) {
        ax = fmaf(bf2f(T[j] & 0xffffu), bf2f(X[j] & 0xffffu), ax);
        ay = fmaf(bf2f(T[j] >> 16), bf2f(X[j] >> 16), ay);
    }
}

__device__ __forceinline__ void eone(
    u32 v0, const u16* __restrict__ Tn, const u16* __restrict__ bx,
    int c2, float& ax, float& ay)
{
    u32 rv = (u32)__builtin_amdgcn_readfirstlane((int)v0);
    int is = (int)(rv >> 16);
    int cs = (int)(rv & 0xffffu);
    u32 T0 = *reinterpret_cast<const u32*>(Tn + (size_t)is * HID + c2);
    u32 X0 = *reinterpret_cast<const u32*>(bx + (size_t)cs * HID + c2);
    ax = fmaf(bf2f(T0 & 0xffffu), bf2f(X0 & 0xffffu), ax);
    ay = fmaf(bf2f(T0 >> 16), bf2f(X0 >> 16), ay);
}

__global__ __launch_bounds__(256) void edge_csr(
    const int* __restrict__ rowstart,   // cur: exclusive scan (row starts)
    const u32* __restrict__ ec,
    const u16* __restrict__ Tn,
    const u16* __restrict__ bx,
    float*     __restrict__ agg,
    int N, int E)
{
    const int lane = threadIdx.x & 63;
    const int slot = threadIdx.x >> 6;
    const int c2   = lane * 2;
    const int r0   = blockIdx.x * RPB;

    const int rA = r0 + slot;
    const int rB = r0 + 4 + slot;

    int eA = 0, eeA = 0, eB = 0, eeB = 0;
    if (rA < N) { eA = rowstart[rA]; eeA = (rA == N - 1) ? E : rowstart[rA + 1]; }
    if (rB < N) { eB = rowstart[rB]; eeB = (rB == N - 1) ? E : rowstart[rB + 1]; }

    float axA = 0.f, ayA = 0.f, axB = 0.f, ayB = 0.f;
    u32 vA[4], vB[4];
    u32 TA[4], TB[4];
    u32 XA[4], XB[4];

    while (eA + 4 <= eeA && eB + 4 <= eeB) {
#pragma unroll
        for (int j = 0; j < 4; ++j) { vA[j] = ec[eA + j]; vB[j] = ec[eB + j]; }
        eload4(vA, Tn, bx, c2, TA, XA);
        eload4(vB, Tn, bx, c2, TB, XB);
        efma4(TA, XA, axA, ayA);
        efma4(TB, XB, axB, ayB);
        eA += 4; eB += 4;
    }
    while (eA + 4 <= eeA) {
#pragma unroll
        for (int j = 0; j < 4; ++j) vA[j] = ec[eA + j];
        eload4(vA, Tn, bx, c2, TA, XA);
        efma4(TA, XA, axA, ayA);
        eA += 4;
    }
    for (; eA < eeA; ++eA) eone(ec[eA], Tn, bx, c2, axA, ayA);
    while (eB + 4 <= eeB) {
#pragma unroll
        for (int j = 0; j < 4; ++j) vB[j] = ec[eB + j];
        eload4(vB, Tn, bx, c2, TB, XB);
        efma4(TB, XB, axB, ayB);
        eB += 4;
    }
    for (; eB < eeB; ++eB) eone(ec[eB], Tn, bx, c2, axB, ayB);

    if (rA < N) {
        float2 o; o.x = axA; o.y = ayA;
        *reinterpret_cast<float2*>(agg + (size_t)rA * HID + c2) = o;
    }
    if (rB < N) {
        float2 o; o.x = axB; o.y = ayB;
        *reinterpret_cast<float2*>(agg + (size_t)rB * HID + c2) = o;
    }
}

// ===========================================================================
// MFMA fused tail: out = ssp(agg @ lin2 + l2b) @ lin_w + lin_b
// ===========================================================================
__global__ __launch_bounds__(256) void tail_mfma(
    const float* __restrict__ agg,
    const u16* __restrict__ lin2T, const float* __restrict__ l2b,
    const u16* __restrict__ linwT, const float* __restrict__ linb,
    float* __restrict__ out, int N)
{
    __shared__ u16 sA[64 * 128];
    __shared__ u16 sT[64 * 128];

    const int tid = threadIdx.x;
    const int r0 = blockIdx.x * 64;

    for (int i = tid; i < 64 * 16; i += 256) {
        int row = i >> 4, ck = i & 15;
        i32x4 pk = (i32x4){0, 0, 0, 0};
        if (r0 + row < N) {
            const float* src = agg + (size_t)(r0 + row) * HID + ck * 8;
            f32x4 a = *reinterpret_cast<const f32x4*>(src);
            f32x4 c = *reinterpret_cast<const f32x4*>(src + 4);
            pk[0] = (int)((u32)f2bf(a[0]) | ((u32)f2bf(a[1]) << 16));
            pk[1] = (int)((u32)f2bf(a[2]) | ((u32)f2bf(a[3]) << 16));
            pk[2] = (int)((u32)f2bf(c[0]) | ((u32)f2bf(c[1]) << 16));
            pk[3] = (int)((u32)f2bf(c[2]) | ((u32)f2bf(c[3]) << 16));
        }
        int byteoff = row * 256 + ((ck * 16) ^ ((row & 7) << 4));
        *reinterpret_cast<i32x4*>(reinterpret_cast<char*>(sA) + byteoff) = pk;
    }
    __syncthreads();

    const int lane = tid & 63;
    const int wv   = tid >> 6;
    const int l15  = lane & 15;
    const int l4   = lane >> 4;
    const int n0   = wv * 32 + l15;
    const int n1   = n0 + 16;

    // GEMM1: t = ssp(agg @ lin2 + l2b)
    {
        bf16x8 bw[2][4];
#pragma unroll
        for (int nt = 0; nt < 2; ++nt)
#pragma unroll
            for (int s = 0; s < 4; ++s) {
                int n = wv * 32 + nt * 16 + l15;
                bw[nt][s] = *reinterpret_cast<const bf16x8*>(lin2T + n * 128 + s * 32 + l4 * 8);
            }

        f32x4 acc[4][2];
#pragma unroll
        for (int mt = 0; mt < 4; ++mt) { acc[mt][0] = (f32x4){0,0,0,0}; acc[mt][1] = (f32x4){0,0,0,0}; }

#pragma unroll
        for (int mt = 0; mt < 4; ++mt)
#pragma unroll
            for (int s = 0; s < 4; ++s) {
                int e = mt * 16 + l15;
                int byteoff = e * 256 + ((s * 64 + l4 * 16) ^ ((e & 7) << 4));
                bf16x8 af = *reinterpret_cast<const bf16x8*>(reinterpret_cast<char*>(sA) + byteoff);
                acc[mt][0] = __builtin_amdgcn_mfma_f32_16x16x32_bf16(af, bw[0][s], acc[mt][0], 0, 0, 0);
                acc[mt][1] = __builtin_amdgcn_mfma_f32_16x16x32_bf16(af, bw[1][s], acc[mt][1], 0, 0, 0);
            }

        const float bb0 = l2b[n0];
        const float bb1 = l2b[n1];
#pragma unroll
        for (int mt = 0; mt < 4; ++mt)
#pragma unroll
            for (int nt = 0; nt < 2; ++nt) {
                const int n = (nt == 0) ? n0 : n1;
                const float bb = (nt == 0) ? bb0 : bb1;
#pragma unroll
                for (int r = 0; r < 4; ++r) {
                    int m = mt * 16 + l4 * 4 + r;
                    float v = sspf(acc[mt][nt][r] + bb);
                    int byteoff = m * 256 + ((n * 2) ^ ((m & 7) << 4));
                    *reinterpret_cast<u16*>(reinterpret_cast<char*>(sT) + byteoff) = f2bf(v);
                }
            }
    }
    __syncthreads();

    // GEMM2: out = t @ lin_w + lin_b
    {
        bf16x8 bw[2][4];
#pragma unroll
        for (int nt = 0; nt < 2; ++nt)
#pragma unroll
            for (int s = 0; s < 4; ++s) {
                int n = wv * 32 + nt * 16 + l15;
                bw[nt][s] = *reinterpret_cast<const bf16x8*>(linwT + n * 128 + s * 32 + l4 * 8);
            }

        f32x4 acc[4][2];
#pragma unroll
        for (int mt = 0; mt < 4; ++mt) { acc[mt][0] = (f32x4){0,0,0,0}; acc[mt][1] = (f32x4){0,0,0,0}; }

#pragma unroll
        for (int mt = 0; mt < 4; ++mt)
#pragma unroll
            for (int s = 0; s < 4; ++s) {
                int e = mt * 16 + l15;
                int byteoff = e * 256 + ((s * 64 + l4 * 16) ^ ((e & 7) << 4));
                bf16x8 af = *reinterpret_cast<const bf16x8*>(reinterpret_cast<char*>(sT) + byteoff);
                acc[mt][0] = __builtin_amdgcn_mfma_f32_16x16x32_bf16(af, bw[0][s], acc[mt][0], 0, 0, 0);
                acc[mt][1] = __builtin_amdgcn_mfma_f32_16x16x32_bf16(af, bw[1][s], acc[mt][1], 0, 0, 0);
            }

        const float cb0 = linb[n0];
        const float cb1 = linb[n1];
#pragma unroll
        for (int mt = 0; mt < 4; ++mt)
#pragma unroll
            for (int nt = 0; nt < 2; ++nt) {
                const int n = (nt == 0) ? n0 : n1;
                const float cb = (nt == 0) ? cb0 : cb1;
#pragma unroll
                for (int r = 0; r < 4; ++r) {
                    int row = r0 + mt * 16 + l4 * 4 + r;
                    if (row < N)
                        out[(size_t)row * HID + n] = acc[mt][nt][r] + cb;
                }
            }
    }
}

// ===========================================================================
extern "C" void kernel_launch(void* const* d_in, const int* in_sizes, int n_in,
                              void* d_out, int out_size, void* d_ws, size_t ws_size,
                              hipStream_t stream)
{
    const float* h    = (const float*)d_in[0];
    const float* pos  = (const float*)d_in[1];
    const int*   eidx = (const int*)  d_in[2];
    const float* w1   = (const float*)d_in[3];
    const float* b1   = (const float*)d_in[4];
    const float* w2   = (const float*)d_in[5];
    const float* b2   = (const float*)d_in[6];
    const float* lin1 = (const float*)d_in[7];
    const float* lin2 = (const float*)d_in[8];
    const float* l2b  = (const float*)d_in[9];
    const float* linw = (const float*)d_in[10];
    const float* linb = (const float*)d_in[11];

    const int N = in_sizes[0] / HID;
    const int E = in_sizes[2] / 2;

    char* ws = (char*)d_ws;
    size_t off = 0;
    auto alloc = [&](size_t bytes) { char* p = ws + off; off = (off + bytes + 255) & ~(size_t)255; return p; };

    u16*    bx    = (u16*)   alloc((size_t)N * HID * sizeof(u16));
    u16*    Tn    = (u16*)   alloc((size_t)TN * HID * sizeof(u16));
    float*  agg   = (float*) alloc((size_t)N * HID * sizeof(float));
    int*    cntp  = (int*)   alloc((size_t)NSL * N * sizeof(int));
    int*    cnt   = (int*)   alloc((size_t)N * sizeof(int));
    int*    cur   = (int*)   alloc((size_t)N * sizeof(int));
    int*    part  = (int*)   alloc(256 * sizeof(int));
    u32*    rec   = (u32*)   alloc((size_t)E * sizeof(u32));
    u32*    ec    = (u32*)   alloc(((size_t)E + 8) * sizeof(u32));
    u16*    lin1T = (u16*)   alloc(128 * 128 * sizeof(u16));
    u16*    lin2T = (u16*)   alloc(128 * 128 * sizeof(u16));
    u16*    linwT = (u16*)   alloc(128 * 128 * sizeof(u16));

    const int nrec = (E + 255) / 256;

    // K1: table + hist + transposes + rec (no global atomics anywhere)
    k1_table_hist_prep<<<TBLB + NRG * NSL + 192 + nrec, 256, 0, stream>>>(
        w1, b1, w2, b2, Tn, eidx, cntp, pos, rec,
        lin1, lin2, linw, lin1T, lin2T, linwT, N, E);

    // K2: fold cntp -> cnt (+ in-place slice prefix) || MFMA node GEMM
    const int nch = (N + SCAN_CHUNK - 1) / SCAN_CHUNK;
    const int ngb = (N + 63) / 64;
    k2_part_mfma<<<nch + ngb, 256, 0, stream>>>(cntp, cnt, part, nch, h, lin1T, bx, N);

    // K3: scan phase 2 -> cur (row START offsets)
    scan_write<<<nch, 256, 0, stream>>>(cnt, part, cur, N);

    // K4: deterministic-offset scatter, zero global atomics
    scatter_sorted<<<NRG * NSL, 256, 0, stream>>>(eidx, rec, cur, cntp, ec, N, E);

    // CSR gather-modulate-sum (rowstart semantics)
    edge_csr<<<(N + RPB - 1) / RPB, 256, 0, stream>>>(cur, ec, Tn, bx, agg, N, E);

    // out = ssp(agg @ lin2 + l2b) @ lin_w + lin_b  (MFMA)
    tail_mfma<<<ngb, 256, 0, stream>>>(agg, lin2T, l2b, linwT, linb, (float*)d_out, N);
}